// Round 6
// baseline (465.148 us; speedup 1.0000x reference)
//
#include <hip/hip_runtime.h>

// GCN 2-layer collapsed (x is [N,1] => layer 1 is rank-1):
//   out[c] = dis[c]*(sum_{r->c} gp[r] + gp[c]) + b2,  gp[r] = (relu(W1*a[r]+b1)@W2)*dis[r]
//   a[r]   = dis[r]*(sum_{r'->r} p[r'] + p[r]),       p[r']=x[r']*dis[r'], dis=1/sqrt(deg+1)
//
// R1: global atomics = 20G/s fabric wall (3.1ms).
// R2: 512-node buckets + LDS atomics (478us); partition 4B scatters = 390MB write-through.
// R3: sort-based partition, 4096 chunks -> only 123 blocks, half the CUs idle (646us).
// R4: 1024 chunks, K=489 (429us). R5: SPLIT=4 slices, occupancy 17%->53%, k_o_split
//     UNCHANGED at 175us, cache-warm replay also 175us => bottleneck is L2->L1 line
//     amplification of random per-lane gathers (16M x 128B ~ 2GB per gather pass).
// R6: second partition level: within each 4096-node col-chunk, sort edges by row>>13
//     (8192-node row windows = 32KB p = L1-resident; ~8 edges per p-line). Gathers become
//     L1 hits; aggregation streams packedB. Partials alias dead packedA.

#define KMAXT 512            // max keys for generic tile-sort partition (path1: 489, path2: 123)

#define PTPB  512            // partition block
#define PU    16             // edges per thread
#define PTILE (PTPB * PU)    // 8192 edges per tile

#define ATPB  256            // aggregation block

// path2 constants
#define RBSH   13            // row-bucket shift (8192-node windows); needs n <= 2^19
#define NRB    64            // row buckets per chunk key space
#define FKEYS  8192          // max fine keys = 128 chunks * 64 rb
#define NSLB   24            // part_b slices per chunk (tile-strided, always correct)
#define BTPB2  512
#define PU2    16
#define BTILE2 (BTPB2 * PU2) // 8192

// ---------- zero ----------
__global__ void k_zero(int* __restrict__ a, int m) {
    int i = blockIdx.x * blockDim.x + threadIdx.x;
    if (i < m) a[i] = 0;
}

// ---------- coarse histogram (path1) ----------
template<int CSH>
__global__ void k_count(const int* __restrict__ col, int ne, int ne4,
                        int* __restrict__ totals, int K) {
    __shared__ int cnt[KMAXT];
    for (int i = threadIdx.x; i < K; i += blockDim.x) cnt[i] = 0;
    __syncthreads();
    int tid = blockIdx.x * blockDim.x + threadIdx.x;
    int stride = gridDim.x * blockDim.x;
    const int4* col4 = (const int4*)col;
    for (int e = tid; e < ne4; e += stride) {
        int4 cc = col4[e];
        atomicAdd(&cnt[cc.x >> CSH], 1);
        atomicAdd(&cnt[cc.y >> CSH], 1);
        atomicAdd(&cnt[cc.z >> CSH], 1);
        atomicAdd(&cnt[cc.w >> CSH], 1);
    }
    for (int e = (ne4 << 2) + tid; e < ne; e += stride)
        atomicAdd(&cnt[col[e] >> CSH], 1);
    __syncthreads();
    for (int i = threadIdx.x; i < K; i += blockDim.x)
        if (cnt[i]) atomicAdd(&totals[i], cnt[i]);
}

// ---------- serial scan (path1, K<=512) ----------
__global__ void k_scan(const int* __restrict__ totals, int* __restrict__ bbase,
                       int* __restrict__ cursor, int K) {
    if (threadIdx.x == 0 && blockIdx.x == 0) {
        int run = 0;
        for (int k = 0; k < K; ++k) { bbase[k] = run; cursor[k] = run; run += totals[k]; }
        bbase[K] = run;
    }
}

// ---------- fine histogram (path2): key = (col>>12)*64 + (row>>13) ----------
__global__ void k_count_fine(const int* __restrict__ row, const int* __restrict__ col,
                             int ne, int ne4, int* __restrict__ totals) {
    __shared__ int cnt[FKEYS];
    for (int i = threadIdx.x; i < FKEYS; i += blockDim.x) cnt[i] = 0;
    __syncthreads();
    int tid = blockIdx.x * blockDim.x + threadIdx.x;
    int stride = gridDim.x * blockDim.x;
    const int4* r4 = (const int4*)row;
    const int4* c4 = (const int4*)col;
    for (int e = tid; e < ne4; e += stride) {
        int4 rr = r4[e];
        int4 cc = c4[e];
        atomicAdd(&cnt[(cc.x >> 12) * NRB + (rr.x >> RBSH)], 1);
        atomicAdd(&cnt[(cc.y >> 12) * NRB + (rr.y >> RBSH)], 1);
        atomicAdd(&cnt[(cc.z >> 12) * NRB + (rr.z >> RBSH)], 1);
        atomicAdd(&cnt[(cc.w >> 12) * NRB + (rr.w >> RBSH)], 1);
    }
    for (int e = (ne4 << 2) + tid; e < ne; e += stride)
        atomicAdd(&cnt[(col[e] >> 12) * NRB + (row[e] >> RBSH)], 1);
    __syncthreads();
    for (int i = threadIdx.x; i < FKEYS; i += blockDim.x)
        if (cnt[i]) atomicAdd(&totals[i], cnt[i]);
}

// ---------- parallel scan of fine keys; also derive chunk bases ----------
__global__ __launch_bounds__(512) void k_scan_fine(
    const int* __restrict__ totals, int* __restrict__ fineBase, int* __restrict__ cursorB,
    int* __restrict__ cbase, int* __restrict__ cursorA, int nkeys, int chunks) {
    __shared__ int part[512];
    int t = threadIdx.x;
    int base = t * 16;
    int loc[16];
    int sum = 0;
#pragma unroll
    for (int j = 0; j < 16; ++j) {
        int k = base + j;
        int v = (k < nkeys) ? totals[k] : 0;
        loc[j] = sum; sum += v;
    }
    part[t] = sum;
    __syncthreads();
    for (int d = 1; d < 512; d <<= 1) {
        int v = (t >= d) ? part[t - d] : 0;
        __syncthreads();
        part[t] += v;
        __syncthreads();
    }
    int pre = (t == 0) ? 0 : part[t - 1];
#pragma unroll
    for (int j = 0; j < 16; ++j) {
        int k = base + j;
        if (k < nkeys) { int b = pre + loc[j]; fineBase[k] = b; cursorB[k] = b; }
    }
    if (t == 0) fineBase[nkeys] = part[511];
    __syncthreads();
    if (t < chunks) { int b = fineBase[t * NRB]; cbase[t] = b; cursorA[t] = b; }
    if (t == 0) cbase[chunks] = part[511];
}

// ---------- tile-local LDS counting sort partition (generic key = col>>CSH) ----------
template<int CSH>
__global__ __launch_bounds__(PTPB) void k_part(
    const int* __restrict__ row, const int* __restrict__ col, int ne,
    int* __restrict__ cursor, int* __restrict__ packed, int K)
{
    constexpr int CN = 1 << CSH;
    __shared__ int s_cnt[KMAXT];
    __shared__ int s_start[KMAXT + 1];
    __shared__ int s_cur[KMAXT];
    __shared__ int s_gbase[KMAXT];
    __shared__ int s_sorted[PTILE];

    int tb = blockIdx.x * PTILE;
    int tilecount = ne - tb;
    if (tilecount > PTILE) tilecount = PTILE;

    for (int i = threadIdx.x; i < K; i += PTPB) s_cnt[i] = 0;
    __syncthreads();

    int r[PU], c[PU];
    const int4* row4 = (const int4*)row;
    const int4* col4 = (const int4*)col;
    int tb4 = tb >> 2;
#pragma unroll
    for (int j = 0; j < PU / 4; ++j) {
        int g4 = tb4 + j * PTPB + threadIdx.x;
        int e = g4 << 2;
        if (e + 3 < ne) {
            int4 rr = row4[g4];
            int4 cc = col4[g4];
            r[4 * j + 0] = rr.x; r[4 * j + 1] = rr.y; r[4 * j + 2] = rr.z; r[4 * j + 3] = rr.w;
            c[4 * j + 0] = cc.x; c[4 * j + 1] = cc.y; c[4 * j + 2] = cc.z; c[4 * j + 3] = cc.w;
        } else {
#pragma unroll
            for (int q = 0; q < 4; ++q) {
                int e2 = e + q;
                if (e2 < ne) { r[4 * j + q] = row[e2]; c[4 * j + q] = col[e2]; }
                else { r[4 * j + q] = 0; c[4 * j + q] = -1; }
            }
        }
    }
#pragma unroll
    for (int j = 0; j < PU; ++j)
        if (c[j] >= 0) atomicAdd(&s_cnt[c[j] >> CSH], 1);
    __syncthreads();

    if (threadIdx.x == 0) {
        int run = 0;
        for (int k = 0; k < K; ++k) { s_start[k] = run; run += s_cnt[k]; }
        s_start[K] = run;
    }
    __syncthreads();
    if ((int)threadIdx.x < K) {
        int n0 = s_cnt[threadIdx.x];
        s_gbase[threadIdx.x] = n0 ? atomicAdd(&cursor[threadIdx.x], n0) : 0;
        s_cur[threadIdx.x] = s_start[threadIdx.x];
    }
    __syncthreads();

#pragma unroll
    for (int j = 0; j < PU; ++j) {
        if (c[j] >= 0) {
            int ck = c[j] >> CSH;
            int pos = atomicAdd(&s_cur[ck], 1);
            s_sorted[pos] = (r[j] << CSH) | (c[j] & (CN - 1));
        }
    }
    __syncthreads();

    for (int i = threadIdx.x; i < tilecount; i += PTPB) {
        int v = s_sorted[i];
        int lo = 0, hi = K;
        while (hi - lo > 1) {
            int mid = (lo + hi) >> 1;
            if (s_start[mid] <= i) lo = mid; else hi = mid;
        }
        packed[s_gbase[lo] + (i - s_start[lo])] = v;
    }
}

// ---------- part_b: within each chunk segment, sort by row bucket (val>>25) ----------
__global__ __launch_bounds__(BTPB2) void k_part_b(
    const int* __restrict__ packedA, const int* __restrict__ cbase,
    int* __restrict__ cursorB, int* __restrict__ packedB, int chunks)
{
    __shared__ int s_cnt[NRB];
    __shared__ int s_start[NRB + 1];
    __shared__ int s_cur[NRB];
    __shared__ int s_gbase[NRB];
    __shared__ int s_sorted[BTILE2];

    int k = blockIdx.x / NSLB, sl = blockIdx.x % NSLB;
    if (k >= chunks) return;
    int seg0 = cbase[k], seg1 = cbase[k + 1];
    for (int t0 = seg0 + sl * BTILE2; t0 < seg1; t0 += NSLB * BTILE2) {
        int cnt = min(BTILE2, seg1 - t0);
        if ((int)threadIdx.x < NRB) s_cnt[threadIdx.x] = 0;
        __syncthreads();
        int v[PU2];
#pragma unroll
        for (int j = 0; j < PU2; ++j) {
            int idx = t0 + j * BTPB2 + (int)threadIdx.x;
            v[j] = (idx < seg1 && idx < t0 + BTILE2) ? packedA[idx] : -1;
            if (v[j] >= 0) atomicAdd(&s_cnt[((unsigned)v[j]) >> 25], 1);
        }
        __syncthreads();
        if (threadIdx.x == 0) {
            int run = 0;
            for (int q = 0; q < NRB; ++q) { s_start[q] = run; run += s_cnt[q]; }
            s_start[NRB] = run;
        }
        __syncthreads();
        if ((int)threadIdx.x < NRB) {
            int c0 = s_cnt[threadIdx.x];
            s_gbase[threadIdx.x] = c0 ? atomicAdd(&cursorB[k * NRB + (int)threadIdx.x], c0) : 0;
            s_cur[threadIdx.x] = s_start[threadIdx.x];
        }
        __syncthreads();
#pragma unroll
        for (int j = 0; j < PU2; ++j) {
            if (v[j] >= 0) {
                int pos = atomicAdd(&s_cur[((unsigned)v[j]) >> 25], 1);
                s_sorted[pos] = v[j];
            }
        }
        __syncthreads();
        for (int i = threadIdx.x; i < cnt; i += BTPB2) {
            int val = s_sorted[i];
            int lo = 0, hi = NRB;
            while (hi - lo > 1) {
                int mid = (lo + hi) >> 1;
                if (s_start[mid] <= i) lo = mid; else hi = mid;
            }
            packedB[s_gbase[lo] + (i - s_start[lo])] = val;
        }
        __syncthreads();
    }
}

// ---------- slice bounds ----------
template<int S>
__device__ inline void slice_bounds(const int* bbase, int k, int s, int& es, int& ee) {
    int e0 = bbase[k], e1 = bbase[k + 1];
    long long len = e1 - e0;
    es = e0 + (int)((len * s) / S);
    ee = e0 + (int)((len * (s + 1)) / S);
}

// ---------- degree partials ----------
template<int CSH, int S>
__global__ __launch_bounds__(ATPB) void k_deg_split(
    const int* __restrict__ packed, const int* __restrict__ bbase,
    int* __restrict__ pcnt, int n)
{
    constexpr int CN = 1 << CSH;
    __shared__ int cnt[CN];
    int k = blockIdx.x / S, s = blockIdx.x % S;
    int node0 = k << CSH;
    int nn = min(CN, n - node0);
    for (int i = threadIdx.x; i < nn; i += ATPB) cnt[i] = 0;
    __syncthreads();
    int es, ee;
    slice_bounds<S>(bbase, k, s, es, ee);
    int a0 = min((es + 3) & ~3, ee);
    int a1 = max(ee & ~3, a0);
    for (int e = es + (int)threadIdx.x; e < a0; e += ATPB)
        atomicAdd(&cnt[packed[e] & (CN - 1)], 1);
    const int4* pk4 = (const int4*)packed;
    for (int i4 = (a0 >> 2) + (int)threadIdx.x; i4 < (a1 >> 2); i4 += ATPB) {
        int4 v = pk4[i4];
        atomicAdd(&cnt[v.x & (CN - 1)], 1);
        atomicAdd(&cnt[v.y & (CN - 1)], 1);
        atomicAdd(&cnt[v.z & (CN - 1)], 1);
        atomicAdd(&cnt[v.w & (CN - 1)], 1);
    }
    for (int e = a1 + (int)threadIdx.x; e < ee; e += ATPB)
        atomicAdd(&cnt[packed[e] & (CN - 1)], 1);
    __syncthreads();
    int* dst = pcnt + (size_t)s * n + node0;
    for (int i = threadIdx.x; i < nn; i += ATPB) dst[i] = cnt[i];
}

// ---------- reduce degree -> dis, p ----------
template<int S>
__global__ void r_dis_p(const float* __restrict__ x, const int* __restrict__ pcnt,
                        float* __restrict__ dis, float* __restrict__ p, int n)
{
    int i = blockIdx.x * blockDim.x + threadIdx.x;
    if (i >= n) return;
    int d = 1;
#pragma unroll
    for (int s = 0; s < S; ++s) d += pcnt[(size_t)s * n + i];
    float ds = 1.0f / sqrtf((float)d);
    dis[i] = ds;
    p[i] = x[i] * ds;
}

// ---------- scalar aggregation partials ----------
template<int CSH, int S>
__global__ __launch_bounds__(ATPB) void k_s_split(
    const int* __restrict__ packed, const int* __restrict__ bbase,
    const float* __restrict__ p, float* __restrict__ ps, int n)
{
    constexpr int CN = 1 << CSH;
    __shared__ float sv[CN];
    int k = blockIdx.x / S, s = blockIdx.x % S;
    int node0 = k << CSH;
    int nn = min(CN, n - node0);
    for (int i = threadIdx.x; i < nn; i += ATPB) sv[i] = 0.0f;
    __syncthreads();
    int es, ee;
    slice_bounds<S>(bbase, k, s, es, ee);
    int a0 = min((es + 3) & ~3, ee);
    int a1 = max(ee & ~3, a0);
    for (int e = es + (int)threadIdx.x; e < a0; e += ATPB) {
        int v = packed[e];
        atomicAdd(&sv[v & (CN - 1)], p[((unsigned)v) >> CSH]);
    }
    const int4* pk4 = (const int4*)packed;
    for (int i4 = (a0 >> 2) + (int)threadIdx.x; i4 < (a1 >> 2); i4 += ATPB) {
        int4 v = pk4[i4];
        atomicAdd(&sv[v.x & (CN - 1)], p[((unsigned)v.x) >> CSH]);
        atomicAdd(&sv[v.y & (CN - 1)], p[((unsigned)v.y) >> CSH]);
        atomicAdd(&sv[v.z & (CN - 1)], p[((unsigned)v.z) >> CSH]);
        atomicAdd(&sv[v.w & (CN - 1)], p[((unsigned)v.w) >> CSH]);
    }
    for (int e = a1 + (int)threadIdx.x; e < ee; e += ATPB) {
        int v = packed[e];
        atomicAdd(&sv[v & (CN - 1)], p[((unsigned)v) >> CSH]);
    }
    __syncthreads();
    float* dst = ps + (size_t)s * n + node0;
    for (int i = threadIdx.x; i < nn; i += ATPB) dst[i] = sv[i];
}

// ---------- reduce s + fused MLP -> gp ----------
template<int S>
__global__ void r_gp(const float* __restrict__ ps, const float* __restrict__ p,
                     const float* __restrict__ dis,
                     const float* __restrict__ W1, const float* __restrict__ b1,
                     const float* __restrict__ W2, float* __restrict__ gp, int n)
{
    int i = blockIdx.x * blockDim.x + threadIdx.x;
    if (i >= n) return;
    float sum = p[i];
#pragma unroll
    for (int s = 0; s < S; ++s) sum += ps[(size_t)s * n + i];
    float d = dis[i];
    float a = d * sum;
    float g0 = 0.0f, g1 = 0.0f;
#pragma unroll
    for (int q = 0; q < 16; ++q) {
        float h = fmaxf(W1[q] * a + b1[q], 0.0f);
        g0 += h * W2[2 * q];
        g1 += h * W2[2 * q + 1];
    }
    ((float2*)gp)[i] = make_float2(g0 * d, g1 * d);
}

// ---------- float2 aggregation partials ----------
template<int CSH, int S>
__global__ __launch_bounds__(ATPB) void k_o_split(
    const int* __restrict__ packed, const int* __restrict__ bbase,
    const float* __restrict__ gp, float* __restrict__ pout, int n)
{
    constexpr int CN = 1 << CSH;
    __shared__ float ox[CN];
    __shared__ float oy[CN];
    int k = blockIdx.x / S, s = blockIdx.x % S;
    int node0 = k << CSH;
    int nn = min(CN, n - node0);
    for (int i = threadIdx.x; i < nn; i += ATPB) { ox[i] = 0.0f; oy[i] = 0.0f; }
    __syncthreads();
    int es, ee;
    slice_bounds<S>(bbase, k, s, es, ee);
    int a0 = min((es + 3) & ~3, ee);
    int a1 = max(ee & ~3, a0);
    const float2* gp2 = (const float2*)gp;
    for (int e = es + (int)threadIdx.x; e < a0; e += ATPB) {
        int v = packed[e];
        float2 g = gp2[((unsigned)v) >> CSH];
        atomicAdd(&ox[v & (CN - 1)], g.x);
        atomicAdd(&oy[v & (CN - 1)], g.y);
    }
    const int4* pk4 = (const int4*)packed;
    for (int i4 = (a0 >> 2) + (int)threadIdx.x; i4 < (a1 >> 2); i4 += ATPB) {
        int4 v = pk4[i4];
        float2 g0 = gp2[((unsigned)v.x) >> CSH];
        float2 g1 = gp2[((unsigned)v.y) >> CSH];
        float2 g2 = gp2[((unsigned)v.z) >> CSH];
        float2 g3 = gp2[((unsigned)v.w) >> CSH];
        atomicAdd(&ox[v.x & (CN - 1)], g0.x);
        atomicAdd(&oy[v.x & (CN - 1)], g0.y);
        atomicAdd(&ox[v.y & (CN - 1)], g1.x);
        atomicAdd(&oy[v.y & (CN - 1)], g1.y);
        atomicAdd(&ox[v.z & (CN - 1)], g2.x);
        atomicAdd(&oy[v.z & (CN - 1)], g2.y);
        atomicAdd(&ox[v.w & (CN - 1)], g3.x);
        atomicAdd(&oy[v.w & (CN - 1)], g3.y);
    }
    for (int e = a1 + (int)threadIdx.x; e < ee; e += ATPB) {
        int v = packed[e];
        float2 g = gp2[((unsigned)v) >> CSH];
        atomicAdd(&ox[v & (CN - 1)], g.x);
        atomicAdd(&oy[v & (CN - 1)], g.y);
    }
    __syncthreads();
    float2* dst = (float2*)pout + (size_t)s * n + node0;
    for (int i = threadIdx.x; i < nn; i += ATPB) dst[i] = make_float2(ox[i], oy[i]);
}

// ---------- reduce -> out ----------
template<int S>
__global__ void r_out(const float* __restrict__ pout, const float* __restrict__ gp,
                      const float* __restrict__ dis, const float* __restrict__ b2,
                      float* __restrict__ out, int n)
{
    int i = blockIdx.x * blockDim.x + threadIdx.x;
    if (i >= n) return;
    const float2* po2 = (const float2*)pout;
    float2 g = ((const float2*)gp)[i];
    float sx = g.x, sy = g.y;
#pragma unroll
    for (int s = 0; s < S; ++s) {
        float2 t = po2[(size_t)s * n + i];
        sx += t.x; sy += t.y;
    }
    float d = dis[i];
    ((float2*)out)[i] = make_float2(d * sx + b2[0], d * sy + b2[1]);
}

// ---------------- R1 fallback (global atomics, correctness-only) ----------------

__global__ void f_init_deg(float* __restrict__ deg, int n) {
    int i = blockIdx.x * blockDim.x + threadIdx.x;
    if (i < n) deg[i] = 1.0f;
}
__global__ void f_deg(const int* __restrict__ col, float* __restrict__ deg, int ne) {
    int tid = blockIdx.x * blockDim.x + threadIdx.x;
    int stride = gridDim.x * blockDim.x;
    for (int e = tid; e < ne; e += stride) atomicAdd(&deg[col[e]], 1.0f);
}
__global__ void f_dis(const float* __restrict__ x, float* __restrict__ deg_dis,
                      float* __restrict__ p, float* __restrict__ s, int n) {
    int i = blockIdx.x * blockDim.x + threadIdx.x;
    if (i >= n) return;
    float dis = 1.0f / sqrtf(deg_dis[i]);
    deg_dis[i] = dis;
    float pv = x[i] * dis;
    p[i] = pv;
    s[i] = pv;
}
__global__ void f_scatter1(const int* __restrict__ row, const int* __restrict__ col,
                           const float* __restrict__ p, float* __restrict__ s, int ne) {
    int tid = blockIdx.x * blockDim.x + threadIdx.x;
    int stride = gridDim.x * blockDim.x;
    for (int e = tid; e < ne; e += stride) atomicAdd(&s[col[e]], p[row[e]]);
}
__global__ void f_node(const float* __restrict__ dis, const float* __restrict__ s,
                       const float* __restrict__ W1, const float* __restrict__ b1,
                       const float* __restrict__ W2,
                       float* __restrict__ gp, float* __restrict__ out, int n) {
    int i = blockIdx.x * blockDim.x + threadIdx.x;
    if (i >= n) return;
    float d = dis[i];
    float a = d * s[i];
    float g0 = 0.0f, g1 = 0.0f;
#pragma unroll
    for (int q = 0; q < 16; ++q) {
        float h = fmaxf(W1[q] * a + b1[q], 0.0f);
        g0 += h * W2[2 * q];
        g1 += h * W2[2 * q + 1];
    }
    ((float2*)gp)[i] = make_float2(g0 * d, g1 * d);
    ((float2*)out)[i] = make_float2(g0 * d, g1 * d);
}
__global__ void f_scatter2(const int* __restrict__ row, const int* __restrict__ col,
                           const float* __restrict__ gp, float* __restrict__ out, int ne) {
    int tid = blockIdx.x * blockDim.x + threadIdx.x;
    int stride = gridDim.x * blockDim.x;
    const float2* gp2 = (const float2*)gp;
    for (int e = tid; e < ne; e += stride) {
        float2 g = gp2[row[e]];
        atomicAdd(&out[2 * col[e]], g.x);
        atomicAdd(&out[2 * col[e] + 1], g.y);
    }
}
__global__ void f_final(const float* __restrict__ dis, const float* __restrict__ b2,
                        float* __restrict__ out, int n) {
    int i = blockIdx.x * blockDim.x + threadIdx.x;
    if (i >= n) return;
    float d = dis[i];
    float2* out2 = (float2*)out;
    float2 t = out2[i];
    out2[i] = make_float2(d * t.x + b2[0], d * t.y + b2[1]);
}

// ---------------- launch ----------------

extern "C" void kernel_launch(void* const* d_in, const int* in_sizes, int n_in,
                              void* d_out, int out_size, void* d_ws, size_t ws_size,
                              hipStream_t stream) {
    const float* x = (const float*)d_in[0];
    const int* edge_index = (const int*)d_in[1];
    const float* W1 = (const float*)d_in[2];
    const float* b1 = (const float*)d_in[3];
    const float* W2 = (const float*)d_in[4];
    const float* b2 = (const float*)d_in[5];
    float* out = (float*)d_out;

    int n = in_sizes[0];
    int ne = in_sizes[1] / 2;
    const int* row = edge_index;
    const int* col = edge_index + ne;

    int ne4 = ((ne & 3) == 0) ? (ne >> 2) : 0;
    int nodeBlocks = (n + 255) / 256;

    // ---------- try path2 (two-level partition) ----------
    {
        int chunks = (n + 4095) >> 12;
        int nkeys = chunks * NRB;
        size_t off = 0;
        auto alloc = [&](size_t bytes) -> char* {
            char* ptr = (char*)d_ws + off;
            off += (bytes + 255) & ~(size_t)255;
            return ptr;
        };
        int* fineTotals = (int*)alloc((size_t)FKEYS * sizeof(int));
        int* fineBase   = (int*)alloc((size_t)(FKEYS + 1) * sizeof(int));
        int* cursorB    = (int*)alloc((size_t)FKEYS * sizeof(int));
        int* cbase      = (int*)alloc((size_t)(chunks + 1) * sizeof(int));
        int* cursorA    = (int*)alloc((size_t)chunks * sizeof(int));
        int* packedA    = (int*)alloc((size_t)ne * sizeof(int));
        int* packedB    = (int*)alloc((size_t)ne * sizeof(int));
        float* dis      = (float*)alloc((size_t)n * sizeof(float));
        float* p        = (float*)alloc((size_t)n * sizeof(float));
        float* gp       = (float*)alloc((size_t)n * 2 * sizeof(float));
        // partials alias packedA (dead after k_part_b) when they fit, else allocate
        size_t partBytes = (size_t)8 * n * 2 * sizeof(float);
        float* partials;
        if (partBytes <= (size_t)ne * sizeof(int)) partials = (float*)packedA;
        else partials = (float*)alloc(partBytes);

        bool ok = (off <= ws_size) && (n <= (1 << 19)) && (chunks >= 1) && (chunks <= 128)
                  && (ne > 0);
        if (ok) {
            int partBlocksA = (ne + PTILE - 1) / PTILE;
            k_zero<<<(FKEYS + 255) / 256, 256, 0, stream>>>(fineTotals, FKEYS);
            k_count_fine<<<512, 256, 0, stream>>>(row, col, ne, ne4, fineTotals);
            k_scan_fine<<<1, 512, 0, stream>>>(fineTotals, fineBase, cursorB, cbase, cursorA,
                                               nkeys, chunks);
            k_part<12><<<partBlocksA, PTPB, 0, stream>>>(row, col, ne, cursorA, packedA, chunks);
            k_part_b<<<chunks * NSLB, BTPB2, 0, stream>>>(packedA, cbase, cursorB, packedB, chunks);
            k_deg_split<12, 8><<<chunks * 8, ATPB, 0, stream>>>(packedB, cbase, (int*)partials, n);
            r_dis_p<8><<<nodeBlocks, 256, 0, stream>>>(x, (const int*)partials, dis, p, n);
            k_s_split<12, 8><<<chunks * 8, ATPB, 0, stream>>>(packedB, cbase, p, partials, n);
            r_gp<8><<<nodeBlocks, 256, 0, stream>>>(partials, p, dis, W1, b1, W2, gp, n);
            k_o_split<12, 8><<<chunks * 8, ATPB, 0, stream>>>(packedB, cbase, gp, partials, n);
            r_out<8><<<nodeBlocks, 256, 0, stream>>>(partials, gp, dis, b2, out, n);
            return;
        }
    }

    // ---------- path1 (R5: single-level 1024-node chunks, SPLIT=4) ----------
    {
        int K = (n + 1023) >> 10;
        size_t off = 0;
        auto alloc = [&](size_t bytes) -> char* {
            char* ptr = (char*)d_ws + off;
            off += (bytes + 255) & ~(size_t)255;
            return ptr;
        };
        int* totals = (int*)alloc((size_t)K * sizeof(int));
        int* bbase  = (int*)alloc((size_t)(K + 1) * sizeof(int));
        int* cursor = (int*)alloc((size_t)K * sizeof(int));
        int* packed = (int*)alloc((size_t)ne * sizeof(int));
        float* dis  = (float*)alloc((size_t)n * sizeof(float));
        float* p    = (float*)alloc((size_t)n * sizeof(float));
        float* gp   = (float*)alloc((size_t)n * 2 * sizeof(float));
        float* partials = (float*)alloc((size_t)4 * n * 2 * sizeof(float));

        bool ok = (off <= ws_size) && (K >= 1) && (K <= KMAXT) && (ne > 0);
        if (ok) {
            int partBlocks = (ne + PTILE - 1) / PTILE;
            k_zero<<<(K + 255) / 256, 256, 0, stream>>>(totals, K);
            k_count<10><<<1024, 256, 0, stream>>>(col, ne, ne4, totals, K);
            k_scan<<<1, 64, 0, stream>>>(totals, bbase, cursor, K);
            k_part<10><<<partBlocks, PTPB, 0, stream>>>(row, col, ne, cursor, packed, K);
            k_deg_split<10, 4><<<K * 4, ATPB, 0, stream>>>(packed, bbase, (int*)partials, n);
            r_dis_p<4><<<nodeBlocks, 256, 0, stream>>>(x, (const int*)partials, dis, p, n);
            k_s_split<10, 4><<<K * 4, ATPB, 0, stream>>>(packed, bbase, p, partials, n);
            r_gp<4><<<nodeBlocks, 256, 0, stream>>>(partials, p, dis, W1, b1, W2, gp, n);
            k_o_split<10, 4><<<K * 4, ATPB, 0, stream>>>(packed, bbase, gp, partials, n);
            r_out<4><<<nodeBlocks, 256, 0, stream>>>(partials, gp, dis, b2, out, n);
            return;
        }
    }

    // ---------- R1 fallback ----------
    {
        float* ws = (float*)d_ws;
        float* deg_dis = ws;
        float* pp = ws + n;
        float* ss = ws + 2 * (size_t)n;
        float* gpp = ws + 3 * (size_t)n;
        int edgeBlocks = 4096;
        f_init_deg<<<nodeBlocks, 256, 0, stream>>>(deg_dis, n);
        f_deg<<<edgeBlocks, 256, 0, stream>>>(col, deg_dis, ne);
        f_dis<<<nodeBlocks, 256, 0, stream>>>(x, deg_dis, pp, ss, n);
        f_scatter1<<<edgeBlocks, 256, 0, stream>>>(row, col, pp, ss, ne);
        f_node<<<nodeBlocks, 256, 0, stream>>>(deg_dis, ss, W1, b1, W2, gpp, out, n);
        f_scatter2<<<edgeBlocks, 256, 0, stream>>>(row, col, gpp, out, ne);
        f_final<<<nodeBlocks, 256, 0, stream>>>(deg_dis, b2, out, n);
    }
}